// Round 3
// baseline (653.218 us; speedup 1.0000x reference)
//
#include <hip/hip_runtime.h>
#include <stdint.h>

#define S_LEN 2048
#define NH    16
#define NB    4
#define DH    64
#define DMODEL 1024

using bf16x8 = __attribute__((ext_vector_type(8))) __bf16;
using f32x4  = __attribute__((ext_vector_type(4))) float;
using f32x16 = __attribute__((ext_vector_type(16))) float;
using us8    = __attribute__((ext_vector_type(8))) unsigned short;

__device__ __forceinline__ unsigned short f2bf_rne(float f) {
    unsigned u = __builtin_bit_cast(unsigned, f);
    return (unsigned short)((u + 0x7FFFu + ((u >> 16) & 1u)) >> 16);
}

__device__ __forceinline__ bf16x8 ld_bf8(const unsigned short* p) {
    return __builtin_bit_cast(bf16x8, *(const us8*)p);
}

__device__ __forceinline__ f32x4 mfma16(bf16x8 a, bf16x8 b, f32x4 c) {
    return __builtin_amdgcn_mfma_f32_16x16x32_bf16(a, b, c, 0, 0, 0);
}

__device__ __forceinline__ f32x16 mfma32(bf16x8 a, bf16x8 b, f32x16 c) {
    return __builtin_amdgcn_mfma_f32_32x32x16_bf16(a, b, c, 0, 0, 0);
}

__device__ __forceinline__ float fast_exp2(float x) {
#if __has_builtin(__builtin_amdgcn_exp2f)
    return __builtin_amdgcn_exp2f(x);
#else
    return __expf(x * 0.69314718056f);
#endif
}

typedef __attribute__((address_space(1))) void* gp1_t;
typedef __attribute__((address_space(3))) void* lp3_t;

__device__ __forceinline__ void gload_lds16(const void* g, void* l) {
    __builtin_amdgcn_global_load_lds((gp1_t)(const_cast<void*>(g)), (lp3_t)l, 16, 0, 0);
}

// ---------------- fp32 -> bf16 convert ----------------
__global__ void cvt_bf16(const float* __restrict__ in, unsigned short* __restrict__ out, int n4) {
    int i = blockIdx.x * 256 + threadIdx.x;
    if (i < n4) {
        float4 v = ((const float4*)in)[i];
        ushort4 o;
        o.x = f2bf_rne(v.x); o.y = f2bf_rne(v.y);
        o.z = f2bf_rne(v.z); o.w = f2bf_rne(v.w);
        ((ushort4*)out)[i] = o;
    }
}

// ---------------- 128x128x32 bf16 MFMA GEMM (K = 1024), NT layout ----------------
// EPI==0: QKV epilogue -> Qb (prescaled by 0.125*log2e), Kb [B,H,S,DH], Vt [B,H,DH,S]
// EPI==1: fp32 out + bias
template <int EPI>
__global__ __launch_bounds__(256) void gemm128(
    const unsigned short* __restrict__ A,
    const unsigned short* __restrict__ W,
    const float* __restrict__ bias,
    float* __restrict__ outF,
    unsigned short* __restrict__ Qb,
    unsigned short* __restrict__ Kb,
    unsigned short* __restrict__ Vt,
    int nTilesN)
{
    __shared__ __align__(16) unsigned short As[128 * 32];
    __shared__ __align__(16) unsigned short Bs[128 * 32];

    const int bm = blockIdx.x / nTilesN;
    const int bn = blockIdx.x % nTilesN;
    const int tileM = bm * 128, tileN = bn * 128;
    const int tid = threadIdx.x, lane = tid & 63, w = tid >> 6;
    const int m16 = lane & 15, quad = lane >> 4;
    const int wm = w >> 1, wn = w & 1;

    f32x4 acc[4][4] = {};

    const int c0 = w * 64 + lane;
    const int r0 = c0 >> 2, k0 = (c0 & 3) * 8;
    const int c1 = (4 + w) * 64 + lane;
    const int r1 = c1 >> 2, k1 = (c1 & 3) * 8;

    const unsigned short* Ag0 = A + (size_t)(tileM + r0) * 1024 + k0;
    const unsigned short* Ag1 = A + (size_t)(tileM + r1) * 1024 + k1;
    const unsigned short* Bg0 = W + (size_t)(tileN + r0) * 1024 + k0;
    const unsigned short* Bg1 = W + (size_t)(tileN + r1) * 1024 + k1;
    unsigned short* lA0 = &As[w * 512];
    unsigned short* lA1 = &As[(4 + w) * 512];
    unsigned short* lB0 = &Bs[w * 512];
    unsigned short* lB1 = &Bs[(4 + w) * 512];

    for (int kk = 0; kk < 1024; kk += 32) {
        gload_lds16(Ag0 + kk, lA0);
        gload_lds16(Ag1 + kk, lA1);
        gload_lds16(Bg0 + kk, lB0);
        gload_lds16(Bg1 + kk, lB1);
        __syncthreads();

        bf16x8 af[4], bf[4];
#pragma unroll
        for (int i = 0; i < 4; i++)
            af[i] = ld_bf8(&As[(wm * 64 + i * 16 + m16) * 32 + quad * 8]);
#pragma unroll
        for (int j = 0; j < 4; j++)
            bf[j] = ld_bf8(&Bs[(wn * 64 + j * 16 + m16) * 32 + quad * 8]);
#pragma unroll
        for (int i = 0; i < 4; i++)
#pragma unroll
            for (int j = 0; j < 4; j++)
                acc[i][j] = mfma16(af[i], bf[j], acc[i][j]);
        __syncthreads();
    }

    // epilogue: C/D layout col = lane&15, row = quad*4 + reg
#pragma unroll
    for (int i = 0; i < 4; i++) {
        const int mrow = tileM + wm * 64 + i * 16 + quad * 4;
#pragma unroll
        for (int j = 0; j < 4; j++) {
            const int nb0 = tileN + wn * 64 + j * 16;
            const int n = nb0 + m16;
            const float bv = bias[n];
            if (EPI == 0) {
                const int hh = nb0 / 192, rem = nb0 % 192;
                const int t = rem / 64, dbase = rem % 64;
                const int d = dbase + m16;
                const int b_ = mrow >> 11, s0 = mrow & 2047;   // 4 r-rows share b_
                const size_t bh = (size_t)b_ * NH + hh;
                if (t == 2) {
                    ushort4 pk;
                    pk.x = f2bf_rne(acc[i][j][0] + bv);
                    pk.y = f2bf_rne(acc[i][j][1] + bv);
                    pk.z = f2bf_rne(acc[i][j][2] + bv);
                    pk.w = f2bf_rne(acc[i][j][3] + bv);
                    *(ushort4*)&Vt[(bh * DH + d) * S_LEN + s0] = pk;  // 4 consecutive s
                } else {
#pragma unroll
                    for (int r = 0; r < 4; r++) {
                        float val = acc[i][j][r] + bv;
                        const size_t idx = (bh * S_LEN + s0 + r) * DH + d;
                        if (t == 0) Qb[idx] = f2bf_rne(val * 0.18033688f); // 0.125*log2e
                        else        Kb[idx] = f2bf_rne(val);
                    }
                }
            } else {
#pragma unroll
                for (int r = 0; r < 4; r++) {
                    const int m = mrow + r;
                    outF[(size_t)m * DMODEL + n] = acc[i][j][r] + bv;
                }
            }
        }
    }
}

// ---------------- fused attention, 32x32 MFMA ----------------
// block = (b, h, 128 q); 4 waves x 32 q-rows each. Chunk = 128 keys staged in LDS.
// QK: mfma32(A=K, B=Q) -> S^T C-layout (col=q=lane&31, row=key=(r&3)+8*(r>>2)+4h).
// P transpose to PV B-operand via lane<->lane^32 shfl exchange (no LDS round trip).
// PV: mfma32(A=V^T, B=P^T) -> O^T (col=q, row=d). Row-sums in VALU from truncated P.
__global__ __launch_bounds__(256, 4) void attn(const unsigned short* __restrict__ Qb,
                                               const unsigned short* __restrict__ Kb,
                                               const unsigned short* __restrict__ Vt,
                                               const float* __restrict__ alibi,
                                               unsigned short* __restrict__ ob) {
    const int blk = blockIdx.x;
    // XCD swizzle: xcd = h&7 -> all 4 batches + all 16 q-tiles of a head-pair on one XCD
    const int xcd   = blk & 7;
    const int inner = blk >> 3;                 // 0..127
    const int hh = (inner & 1) * 8 + xcd;
    const int b_ = (inner >> 1) & 3;
    const int qt = inner >> 3;                  // 0..15
    const int tid = threadIdx.x, lane = tid & 63, w = tid >> 6;
    const int l31 = lane & 31, h = lane >> 5;
    const int q0 = qt * 128;
    const size_t bh = (size_t)b_ * NH + hh;

    const unsigned short* Kp = Kb + bh * S_LEN * DH;
    const unsigned short* Vp = Vt + bh * DH * S_LEN;

    __shared__ __align__(16) unsigned short Ks[128 * 64];   // [key][d], chunk^(key&7) swizzle
    __shared__ __align__(16) unsigned short Vs[64 * 128];   // [d][key], chunk^(d&15) swizzle

    // Q as B-operand: lane q=l31, k-elems d = kd*16 + h*8 + j  (prescaled by 0.125*log2e)
    const int qrow = q0 + w * 32 + l31;
    bf16x8 qfrag[4];
#pragma unroll
    for (int kd = 0; kd < 4; kd++)
        qfrag[kd] = ld_bf8(Qb + (bh * S_LEN + qrow) * DH + kd * 16 + h * 8);

    const float* Ap = alibi + ((size_t)hh * S_LEN + qrow) * S_LEN + h * 4;

    // staging offsets: global-side swizzle, LDS dest lane-contiguous
    int koff[4], voff[4];
#pragma unroll
    for (int i = 0; i < 4; i++) {
        const int u = i * 256 + w * 64 + lane;
        const int kr = u >> 3, kc_ = u & 7;
        koff[i] = kr * DH + (kc_ ^ (kr & 7)) * 8;
        const int vd = u >> 4, vc = u & 15;
        voff[i] = vd * S_LEN + (vc ^ (vd & 15)) * 8;
    }

    f32x16 oacc[2] = {};
    float ssum = 0.0f;

    for (int kc = 0; kc < S_LEN; kc += 128) {
        __syncthreads();  // prior chunk's reads done before overwrite
#pragma unroll
        for (int i = 0; i < 4; i++)
            gload_lds16(Kp + (size_t)kc * DH + koff[i], &Ks[(i * 256 + w * 64) * 8]);
#pragma unroll
        for (int i = 0; i < 4; i++)
            gload_lds16(Vp + kc + voff[i], &Vs[(i * 256 + w * 64) * 8]);
        __syncthreads();  // staging visible

#pragma unroll
        for (int kt = 0; kt < 4; kt++) {
            // QK: 32 keys x 32 q, accumulate over d
            f32x16 sacc = {};
#pragma unroll
            for (int kd = 0; kd < 4; kd++) {
                const bf16x8 kf =
                    ld_bf8(&Ks[(kt * 32 + l31) * DH + (((kd * 2 + h) ^ (l31 & 7)) * 8)]);
                sacc = mfma32(kf, qfrag[kd], sacc);
            }
            // alibi + exp2; truncate to bf16; pack; VALU row-sum of truncated values
            unsigned Sd[8];
#pragma unroll
            for (int g = 0; g < 4; g++) {
                const float4 al = *(const float4*)(Ap + kc + kt * 32 + g * 8);
                unsigned u0 = __builtin_bit_cast(unsigned,
                    fast_exp2(__builtin_fmaf(al.x, 1.44269504f, sacc[4 * g + 0]))) & 0xFFFF0000u;
                unsigned u1 = __builtin_bit_cast(unsigned,
                    fast_exp2(__builtin_fmaf(al.y, 1.44269504f, sacc[4 * g + 1]))) & 0xFFFF0000u;
                unsigned u2 = __builtin_bit_cast(unsigned,
                    fast_exp2(__builtin_fmaf(al.z, 1.44269504f, sacc[4 * g + 2]))) & 0xFFFF0000u;
                unsigned u3 = __builtin_bit_cast(unsigned,
                    fast_exp2(__builtin_fmaf(al.w, 1.44269504f, sacc[4 * g + 3]))) & 0xFFFF0000u;
                ssum += (__builtin_bit_cast(float, u0) + __builtin_bit_cast(float, u1)) +
                        (__builtin_bit_cast(float, u2) + __builtin_bit_cast(float, u3));
                Sd[2 * g]     = (u0 >> 16) | u1;
                Sd[2 * g + 1] = (u2 >> 16) | u3;
            }
            // exchange with lane^32 to build PV B-fragments (lane q=l31, k = h*8+j)
            const unsigned r0 = (unsigned)__shfl_xor((int)(h ? Sd[0] : Sd[2]), 32);
            const unsigned r1 = (unsigned)__shfl_xor((int)(h ? Sd[1] : Sd[3]), 32);
            const unsigned r2 = (unsigned)__shfl_xor((int)(h ? Sd[4] : Sd[6]), 32);
            const unsigned r3 = (unsigned)__shfl_xor((int)(h ? Sd[5] : Sd[7]), 32);
            uint4 f1, f2;
            if (h == 0) {
                f1 = make_uint4(Sd[0], Sd[1], r0, r1);
                f2 = make_uint4(Sd[4], Sd[5], r2, r3);
            } else {
                f1 = make_uint4(r0, r1, Sd[2], Sd[3]);
                f2 = make_uint4(r2, r3, Sd[6], Sd[7]);
            }
            const bf16x8 pf1 = __builtin_bit_cast(bf16x8, f1);  // keys kt*32 + 0..15
            const bf16x8 pf2 = __builtin_bit_cast(bf16x8, f2);  // keys kt*32 + 16..31
            // PV: O^T += V^T * P^T
#pragma unroll
            for (int dblk = 0; dblk < 2; dblk++) {
                const bf16x8 vf1 = ld_bf8(
                    &Vs[(dblk * 32 + l31) * 128 + (((kt * 4 + h) ^ (l31 & 15)) * 8)]);
                oacc[dblk] = mfma32(vf1, pf1, oacc[dblk]);
                const bf16x8 vf2 = ld_bf8(
                    &Vs[(dblk * 32 + l31) * 128 + (((kt * 4 + 2 + h) ^ (l31 & 15)) * 8)]);
                oacc[dblk] = mfma32(vf2, pf2, oacc[dblk]);
            }
        }
    }

    // finalize: combine the two half-lane key-subsets, normalize, store bf16 [B,S,D]
    const float tot = ssum + __shfl_xor(ssum, 32);
    const float rinv = 1.0f / tot;
    unsigned short* orow = ob + ((size_t)b_ * S_LEN + qrow) * DMODEL + hh * DH;
#pragma unroll
    for (int dblk = 0; dblk < 2; dblk++)
#pragma unroll
        for (int rg = 0; rg < 4; rg++) {
            ushort4 pk;
            pk.x = f2bf_rne(oacc[dblk][4 * rg + 0] * rinv);
            pk.y = f2bf_rne(oacc[dblk][4 * rg + 1] * rinv);
            pk.z = f2bf_rne(oacc[dblk][4 * rg + 2] * rinv);
            pk.w = f2bf_rne(oacc[dblk][4 * rg + 3] * rinv);
            *(ushort4*)(orow + dblk * 32 + rg * 8 + h * 4) = pk;
        }
}

extern "C" void kernel_launch(void* const* d_in, const int* in_sizes, int n_in,
                              void* d_out, int out_size, void* d_ws, size_t ws_size,
                              hipStream_t stream) {
    (void)in_sizes; (void)n_in; (void)out_size; (void)ws_size;
    const float* x      = (const float*)d_in[0];
    const float* alibi  = (const float*)d_in[1];
    const float* w_qkv  = (const float*)d_in[2];
    const float* b_qkv  = (const float*)d_in[3];
    const float* w_o    = (const float*)d_in[4];
    const float* b_o    = (const float*)d_in[5];
    float* out = (float*)d_out;

    char* ws = (char*)d_ws;
    unsigned short* xb    = (unsigned short*)(ws);              // 16.78 MB
    unsigned short* wqkvb = (unsigned short*)(ws + 16777216);   //  6.29 MB
    unsigned short* wob   = (unsigned short*)(ws + 23068672);   //  2.10 MB
    unsigned short* Qb    = (unsigned short*)(ws + 25165824);   // 16.78 MB
    unsigned short* Kb    = (unsigned short*)(ws + 41943040);   // 16.78 MB
    unsigned short* Vt    = (unsigned short*)(ws + 58720256);   // 16.78 MB
    unsigned short* ob    = (unsigned short*)(ws + 75497472);   // 16.78 MB (total ~92 MB)

    cvt_bf16<<<8192, 256, 0, stream>>>(x, xb, 8388608 / 4);
    cvt_bf16<<<3072, 256, 0, stream>>>(w_qkv, wqkvb, 3145728 / 4);
    cvt_bf16<<<1024, 256, 0, stream>>>(w_o, wob, 1048576 / 4);

    gemm128<0><<<64 * 24, 256, 0, stream>>>(xb, wqkvb, b_qkv, nullptr, Qb, Kb, Vt, 24);
    attn<<<1024, 256, 0, stream>>>(Qb, Kb, Vt, alibi, ob);
    gemm128<1><<<64 * 8, 256, 0, stream>>>(ob, wob, b_o, out, nullptr, nullptr, nullptr, 8);
}